// Round 5
// baseline (120.354 us; speedup 1.0000x reference)
//
#include <hip/hip_runtime.h>
#include <hip/hip_bf16.h>

#define BB 8
#define SS 8192
#define FF 512
#define EE 128
#define CC 1000

typedef __bf16 bf16x8 __attribute__((ext_vector_type(8)));
typedef float  f32x4  __attribute__((ext_vector_type(4)));

// ---------------- K0: transpose-convert W (F,E) f32 -> Wt (E,F) bf16 ----------------
__global__ void k0_wt(const float* __restrict__ W, __bf16* __restrict__ Wt) {
    int idx = blockIdx.x * 256 + threadIdx.x;   // 65536 = F*E
    int e = idx & (EE - 1);
    int f = idx >> 7;
    Wt[e * FF + f] = (__bf16)W[f * EE + e];
}

// ---------------- FUSED: barrier-free direct-stream diff-GEMM -> exp -> weighted sums ----
// grid = 512 blocks (b = bid>>6, chunk = bid&63 of 128 rows), 256 threads (4 waves)
// Phase 1 has NO LDS staging and NO barriers: every MFMA operand is loaded directly
// (A rows from sx in f32 + reg diff/cvt; B cols from L2-resident Wt; x from L1),
// with loop-invariant bases + immediate offsets and a 1-step-ahead register double-set.
__global__ __launch_bounds__(256, 2) void k_fused(
    const float* __restrict__ x,          // (B,F)
    const float* __restrict__ sx,         // (B,S,F)
    const __bf16* __restrict__ Wt,        // (E,F) bf16
    const float* __restrict__ y,          // (B,S,C)
    float* __restrict__ pout,             // (B,64,C) partial numerators
    float* __restrict__ pden)             // (B,64)   partial denominators
{
    __shared__ float scp[2][128];
    __shared__ float wv[128];

    const int tid   = threadIdx.x;
    const int b     = blockIdx.x >> 6;
    const int chunk = blockIdx.x & 63;
    const int srow0 = chunk << 7;

    const int lane = tid & 63;
    const int w    = tid >> 6;        // wave 0..3
    const int wrow = (w >> 1) * 64;   // wave tile: 64 rows x 64 cols
    const int wcol = (w & 1) * 64;
    const int lg   = lane >> 4;       // k-group 0..3 (8 k-elements each)
    const int lr   = lane & 15;

    // loop-invariant fragment base pointers (all k-offsets become immediates)
    const float* Arow[4];
    #pragma unroll
    for (int m = 0; m < 4; m++)
        Arow[m] = sx + ((size_t)b * SS + srow0 + wrow + m * 16 + lr) * FF + lg * 8;
    const __bf16* Bcol[4];
    #pragma unroll
    for (int n = 0; n < 4; n++)
        Bcol[n] = Wt + (size_t)(wcol + n * 16 + lr) * FF + lg * 8;
    const float* xp = x + b * FF + lg * 8;

    f32x4 acc[4][4];
    #pragma unroll
    for (int m = 0; m < 4; m++)
        #pragma unroll
        for (int n = 0; n < 4; n++) { f32x4 z = {0.f, 0.f, 0.f, 0.f}; acc[m][n] = z; }

    // two named register sets (even/odd step) — all indices compile-time
    float4 sE[4][2], sO[4][2], xE[2], xO[2];
    bf16x8 bE[4], bO[4];

    auto LOADSET = [&](int t, float4 (&sS)[4][2], float4 (&xS)[2], bf16x8 (&bS)[4]) {
        #pragma unroll
        for (int m = 0; m < 4; m++)
            #pragma unroll
            for (int h = 0; h < 2; h++)
                sS[m][h] = *(const float4*)(Arow[m] + t * 32 + h * 4);
        #pragma unroll
        for (int h = 0; h < 2; h++)
            xS[h] = *(const float4*)(xp + t * 32 + h * 4);
        #pragma unroll
        for (int n = 0; n < 4; n++)
            bS[n] = *(const bf16x8*)(Bcol[n] + t * 32);
    };
    auto COMPUTE = [&](float4 (&sS)[4][2], float4 (&xS)[2], bf16x8 (&bS)[4]) {
        bf16x8 af[4];
        #pragma unroll
        for (int m = 0; m < 4; m++) {
            __bf16 d[8];
            #pragma unroll
            for (int h = 0; h < 2; h++) {
                d[4*h+0] = (__bf16)(xS[h].x - sS[m][h].x);
                d[4*h+1] = (__bf16)(xS[h].y - sS[m][h].y);
                d[4*h+2] = (__bf16)(xS[h].z - sS[m][h].z);
                d[4*h+3] = (__bf16)(xS[h].w - sS[m][h].w);
            }
            af[m] = *(bf16x8*)d;
        }
        #pragma unroll
        for (int m = 0; m < 4; m++)
            #pragma unroll
            for (int n = 0; n < 4; n++)
                acc[m][n] = __builtin_amdgcn_mfma_f32_16x16x32_bf16(af[m], bS[n], acc[m][n], 0, 0, 0);
    };

    // ---- Phase 1: K-loop, fully unrolled, 1-step-ahead, barrier-free ----
    LOADSET(0, sE, xE, bE);
    #pragma unroll
    for (int t = 0; t < 16; t++) {
        if (t + 1 < 16) {
            if (t & 1) LOADSET(t + 1, sE, xE, bE);
            else       LOADSET(t + 1, sO, xO, bO);
        }
        if (t & 1) COMPUTE(sO, xO, bO);
        else       COMPUTE(sE, xE, bE);
    }

    // ---- Epilogue: per-row ||.||^2 -> wv[row] = exp(-sqrt(.)) ----
    // C/D layout: col = wcol + n*16 + lr ; row = wrow + m*16 + lg*4 + j
    float rp[4][4];
    #pragma unroll
    for (int m = 0; m < 4; m++)
        #pragma unroll
        for (int j = 0; j < 4; j++) {
            float s = 0.f;
            #pragma unroll
            for (int n = 0; n < 4; n++) { float v = acc[m][n][j]; s += v * v; }
            rp[m][j] = s;
        }
    #pragma unroll
    for (int mask = 1; mask < 16; mask <<= 1)
        #pragma unroll
        for (int m = 0; m < 4; m++)
            #pragma unroll
            for (int j = 0; j < 4; j++)
                rp[m][j] += __shfl_xor(rp[m][j], mask);

    if (lr == 0) {
        #pragma unroll
        for (int m = 0; m < 4; m++)
            #pragma unroll
            for (int j = 0; j < 4; j++)
                scp[w & 1][wrow + m * 16 + lg * 4 + j] = rp[m][j];
    }
    __syncthreads();
    if (tid < 128)
        wv[tid] = expf(-sqrtf(scp[0][tid] + scp[1][tid]));
    __syncthreads();

    // partial denominator: wave 0 reduces wv[0..127]
    if (w == 0) {
        float d = wv[lane] + wv[lane + 64];
        #pragma unroll
        for (int mask = 1; mask < 64; mask <<= 1)
            d += __shfl_xor(d, mask);
        if (lane == 0) pden[b * 64 + chunk] = d;
    }

    // ---- Phase 2: weighted partial sum over support_y (128 rows x 1000 classes) ----
    if (tid < 250) {
        float a0 = 0.f, a1 = 0.f, a2 = 0.f, a3 = 0.f;
        const float* base = y + ((size_t)b * SS + srow0) * CC + tid * 4;
        #pragma unroll 4
        for (int r = 0; r < 128; r++) {
            float4 v = *(const float4*)(base + (size_t)r * CC);
            float wgt = wv[r];
            a0 += wgt * v.x; a1 += wgt * v.y; a2 += wgt * v.z; a3 += wgt * v.w;
        }
        float4 res = {a0, a1, a2, a3};
        *(float4*)(pout + ((size_t)(b * 64 + chunk)) * CC + tid * 4) = res;
    }
}

// ---------------- K4: final reduction over 64 chunks ----------------
__global__ void k4_final(const float* __restrict__ pout, const float* __restrict__ pden,
                         float* __restrict__ out) {
    int idx = blockIdx.x * 256 + threadIdx.x;
    if (idx >= BB * CC) return;
    int b = idx / CC, c = idx % CC;
    float den = 0.f;
    #pragma unroll 8
    for (int k = 0; k < 64; k++) den += pden[b * 64 + k];
    float num = 0.f;
    #pragma unroll 8
    for (int k = 0; k < 64; k++) num += pout[((size_t)(b * 64 + k)) * CC + c];
    out[idx] = num / den;
}

extern "C" void kernel_launch(void* const* d_in, const int* in_sizes, int n_in,
                              void* d_out, int out_size, void* d_ws, size_t ws_size,
                              hipStream_t stream) {
    const float* x  = (const float*)d_in[0];
    const float* sx = (const float*)d_in[1];
    const float* sy = (const float*)d_in[2];
    const float* W  = (const float*)d_in[3];

    char* ws = (char*)d_ws;
    __bf16* Wt   = (__bf16*)(ws);                        // 131072 B
    float*  pout = (float*)(ws + 131072);                // 2048000 B
    float*  pden = (float*)(ws + 131072 + 2048000);      // 2048 B

    k0_wt<<<256, 256, 0, stream>>>(W, Wt);
    k_fused<<<512, 256, 0, stream>>>(x, sx, Wt, sy, pout, pden);
    k4_final<<<32, 256, 0, stream>>>(pout, pden, (float*)d_out);
}

// Round 6
// 92.867 us; speedup vs baseline: 1.2960x; 1.2960x over previous
//
#include <hip/hip_runtime.h>
#include <hip/hip_bf16.h>

#define BB 8
#define SS 8192
#define FF 512
#define EE 128
#define CC 1000

typedef __bf16 bf16x8 __attribute__((ext_vector_type(8)));
typedef float  f32x4  __attribute__((ext_vector_type(4)));

// ---------------- K0: transpose-convert W (F,E) f32 -> Wt (E,F) bf16 ----------------
__global__ void k0_wt(const float* __restrict__ W, __bf16* __restrict__ Wt) {
    int idx = blockIdx.x * 256 + threadIdx.x;   // 65536 = F*E
    int e = idx & (EE - 1);
    int f = idx >> 7;
    Wt[e * FF + f] = (__bf16)W[f * EE + e];
}

// ---------------- FUSED: scores -> exp weights -> weighted partial sums ----------------
// grid = 512 blocks (b = bid>>6, chunk = bid&63 of 128 rows), 512 threads (8 waves)
// Same 128x128 tile / 16-step loop as the 89.2us version; 8 waves -> 4 waves/SIMD
// resident (2 blocks/CU) for latency hiding. launch_bounds(512,4) caps VGPR at 128.
__global__ __launch_bounds__(512, 4) void k_fused(
    const float* __restrict__ x,          // (B,F)
    const float* __restrict__ sx,         // (B,S,F)
    const __bf16* __restrict__ Wt,        // (E,F) bf16
    const float* __restrict__ y,          // (B,S,C)
    float* __restrict__ pout,             // (B,64,C) partial numerators
    float* __restrict__ pden)             // (B,64)   partial denominators
{
    __shared__ __bf16 lA[2][4][128][8];   // 16 KB diff tile (128 rows x 32 k)
    __shared__ __bf16 lB[2][4][128][8];   // 16 KB W tile (128 e x 32 k)
    __shared__ float  scp[2][128];
    __shared__ float  wv[128];

    const int tid   = threadIdx.x;
    const int b     = blockIdx.x >> 6;
    const int chunk = blockIdx.x & 63;
    const int srow0 = chunk << 7;
    const float* Xb = sx + ((size_t)b * SS + srow0) * FF;
    const float* xb = x + b * FF;

    // staging: 4 threads per row, 8 consecutive floats each (128B/row, perfectly coalesced)
    const int rowS = tid >> 2;        // 0..127 (row for A, e for B)
    const int kq   = tid & 3;         // k-group 0..3 (8 k-elements each)

    const int lane = tid & 63;
    const int w    = tid >> 6;        // wave 0..7
    const int wrow = (w >> 1) * 32;   // wave tile: 32 rows x 64 cols
    const int wcol = (w & 1) * 64;
    const int lg   = lane >> 4;       // k-group 0..3
    const int lr   = lane & 15;

    f32x4 acc[2][4];
    #pragma unroll
    for (int m = 0; m < 2; m++)
        #pragma unroll
        for (int n = 0; n < 4; n++) { f32x4 z = {0.f, 0.f, 0.f, 0.f}; acc[m][n] = z; }

    float4 sReg[2], xReg[2];
    bf16x8 bReg;

    auto LOADT = [&](int t) {
        const float* pS = Xb + (size_t)rowS * FF + t * 32 + kq * 8;
        const float* pX = xb + t * 32 + kq * 8;
        #pragma unroll
        for (int i = 0; i < 2; i++) {
            sReg[i] = *(const float4*)(pS + 4 * i);
            xReg[i] = *(const float4*)(pX + 4 * i);
        }
        bReg = *(const bf16x8*)(Wt + (size_t)rowS * FF + t * 32 + kq * 8);
    };
    auto WRITET = [&](int buf) {
        __bf16 d[8];
        #pragma unroll
        for (int i = 0; i < 2; i++) {
            d[4*i+0] = (__bf16)(xReg[i].x - sReg[i].x);
            d[4*i+1] = (__bf16)(xReg[i].y - sReg[i].y);
            d[4*i+2] = (__bf16)(xReg[i].z - sReg[i].z);
            d[4*i+3] = (__bf16)(xReg[i].w - sReg[i].w);
        }
        *(bf16x8*)&lA[buf][kq][rowS][0] = *(bf16x8*)&d[0];
        *(bf16x8*)&lB[buf][kq][rowS][0] = bReg;
    };

    // ---- Phase 1: diff-GEMM over K=512, tile 128x128 ----
    LOADT(0);
    WRITET(0);
    __syncthreads();

    for (int t = 0; t < 16; t++) {
        const int cur = t & 1;
        if (t < 15) LOADT(t + 1);
        bf16x8 af[2], bfr[4];
        #pragma unroll
        for (int m = 0; m < 2; m++)
            af[m] = *(const bf16x8*)&lA[cur][lg][wrow + m * 16 + lr][0];
        #pragma unroll
        for (int n = 0; n < 4; n++)
            bfr[n] = *(const bf16x8*)&lB[cur][lg][wcol + n * 16 + lr][0];
        #pragma unroll
        for (int m = 0; m < 2; m++)
            #pragma unroll
            for (int n = 0; n < 4; n++)
                acc[m][n] = __builtin_amdgcn_mfma_f32_16x16x32_bf16(af[m], bfr[n], acc[m][n], 0, 0, 0);
        if (t < 15) WRITET(cur ^ 1);
        __syncthreads();
    }

    // ---- Epilogue: per-row ||.||^2 -> wv[row] = exp(-sqrt(.)) ----
    // C/D layout: col = wcol + n*16 + lr ; row = wrow + m*16 + lg*4 + j
    float rp[2][4];
    #pragma unroll
    for (int m = 0; m < 2; m++)
        #pragma unroll
        for (int j = 0; j < 4; j++) {
            float s = 0.f;
            #pragma unroll
            for (int n = 0; n < 4; n++) { float v = acc[m][n][j]; s += v * v; }
            rp[m][j] = s;
        }
    #pragma unroll
    for (int mask = 1; mask < 16; mask <<= 1)
        #pragma unroll
        for (int m = 0; m < 2; m++)
            #pragma unroll
            for (int j = 0; j < 4; j++)
                rp[m][j] += __shfl_xor(rp[m][j], mask);

    if (lr == 0) {
        #pragma unroll
        for (int m = 0; m < 2; m++)
            #pragma unroll
            for (int j = 0; j < 4; j++)
                scp[w & 1][wrow + m * 16 + lg * 4 + j] = rp[m][j];
    }
    __syncthreads();
    if (tid < 128)
        wv[tid] = expf(-sqrtf(scp[0][tid] + scp[1][tid]));
    __syncthreads();

    // partial denominator: wave 0 reduces wv[0..127]
    if (w == 0) {
        float d = wv[lane] + wv[lane + 64];
        #pragma unroll
        for (int mask = 1; mask < 64; mask <<= 1)
            d += __shfl_xor(d, mask);
        if (lane == 0) pden[b * 64 + chunk] = d;
    }

    // ---- Phase 2: weighted partial sum over support_y (128 rows x 1000 classes) ----
    if (tid < 500) {
        float a0 = 0.f, a1 = 0.f;
        const float* base = y + ((size_t)b * SS + srow0) * CC + tid * 2;
        #pragma unroll 8
        for (int r = 0; r < 128; r++) {
            float2 v = *(const float2*)(base + (size_t)r * CC);
            float wgt = wv[r];
            a0 += wgt * v.x; a1 += wgt * v.y;
        }
        float2 res = {a0, a1};
        *(float2*)(pout + ((size_t)(b * 64 + chunk)) * CC + tid * 2) = res;
    }
}

// ---------------- K4: final reduction over 64 chunks ----------------
__global__ void k4_final(const float* __restrict__ pout, const float* __restrict__ pden,
                         float* __restrict__ out) {
    int idx = blockIdx.x * 256 + threadIdx.x;
    if (idx >= BB * CC) return;
    int b = idx / CC, c = idx % CC;
    float den = 0.f;
    #pragma unroll 8
    for (int k = 0; k < 64; k++) den += pden[b * 64 + k];
    float num = 0.f;
    #pragma unroll 8
    for (int k = 0; k < 64; k++) num += pout[((size_t)(b * 64 + k)) * CC + c];
    out[idx] = num / den;
}

extern "C" void kernel_launch(void* const* d_in, const int* in_sizes, int n_in,
                              void* d_out, int out_size, void* d_ws, size_t ws_size,
                              hipStream_t stream) {
    const float* x  = (const float*)d_in[0];
    const float* sx = (const float*)d_in[1];
    const float* sy = (const float*)d_in[2];
    const float* W  = (const float*)d_in[3];

    char* ws = (char*)d_ws;
    __bf16* Wt   = (__bf16*)(ws);                        // 131072 B
    float*  pout = (float*)(ws + 131072);                // 2048000 B
    float*  pden = (float*)(ws + 131072 + 2048000);      // 2048 B

    k0_wt<<<256, 256, 0, stream>>>(W, Wt);
    k_fused<<<512, 512, 0, stream>>>(x, sx, Wt, sy, pout, pden);
    k4_final<<<32, 256, 0, stream>>>(pout, pden, (float*)d_out);
}

// Round 7
// 92.230 us; speedup vs baseline: 1.3049x; 1.0069x over previous
//
#include <hip/hip_runtime.h>
#include <hip/hip_bf16.h>

#define BB 8
#define SS 8192
#define FF 512
#define EE 128
#define CC 1000

typedef __bf16 bf16x8 __attribute__((ext_vector_type(8)));
typedef float  f32x4  __attribute__((ext_vector_type(4)));

// Relaxed barrier: ds-write visibility only, NO vmcnt drain (prefetch survives).
#define BAR_RELAXED() do { \
    asm volatile("s_waitcnt lgkmcnt(0)" ::: "memory"); \
    __builtin_amdgcn_s_barrier(); \
} while (0)

// ---------------- K0: transpose-convert W (F,E) f32 -> Wt (E,F) bf16 ----------------
__global__ void k0_wt(const float* __restrict__ W, __bf16* __restrict__ Wt) {
    int idx = blockIdx.x * 256 + threadIdx.x;   // 65536 = F*E
    int e = idx & (EE - 1);
    int f = idx >> 7;
    Wt[e * FF + f] = (__bf16)W[f * EE + e];
}

// ---------------- FUSED: scores -> exp weights -> weighted partial sums ----------------
// grid = 512 blocks (b = bid>>6, chunk = bid&63 of 128 rows), 256 threads (4 waves)
// K-loop: 2-step-ahead sx register prefetch + RAW s_barrier (no vmcnt drain) so the
// prefetch spans barriers. Load order per step: [x,W of t+1] then [sx of t+2], so the
// WRITE's dep-wait is a counted vmcnt(4) leaving the sx prefetch in flight.
__global__ __launch_bounds__(256) void k_fused(
    const float* __restrict__ x,          // (B,F)
    const float* __restrict__ sx,         // (B,S,F)
    const __bf16* __restrict__ Wt,        // (E,F) bf16
    const float* __restrict__ y,          // (B,S,C)
    float* __restrict__ pout,             // (B,64,C) partial numerators
    float* __restrict__ pden)             // (B,64)   partial denominators
{
    __shared__ __bf16 lA[2][4][128][8];   // 16 KB diff tile (128 rows x 32 k)
    __shared__ __bf16 lB[2][4][128][8];   // 16 KB W tile (128 e x 32 k)
    __shared__ float  scp[2][128];
    __shared__ float  wv[128];

    const int tid   = threadIdx.x;
    const int b     = blockIdx.x >> 6;
    const int chunk = blockIdx.x & 63;
    const int srow0 = chunk << 7;
    const float* Xb = sx + ((size_t)b * SS + srow0) * FF;
    const float* xb = x + b * FF;

    const int row  = tid >> 1;        // 0..127 (also 'e' for B staging)
    const int kh   = tid & 1;         // which 16-float half of the 32-k step
    const int lane = tid & 63;
    const int w    = tid >> 6;        // wave 0..3
    const int wrow = (w >> 1) * 64;
    const int wcol = (w & 1) * 64;
    const int lg   = lane >> 4;       // k-group 0..3
    const int lr   = lane & 15;

    f32x4 acc[4][4];
    #pragma unroll
    for (int m = 0; m < 4; m++)
        #pragma unroll
        for (int n = 0; n < 4; n++) { f32x4 z = {0.f, 0.f, 0.f, 0.f}; acc[m][n] = z; }

    // two in-flight sx register sets (2-step-ahead pipeline); x/W single set (1-ahead)
    float4 sA[4], sB[4];
    float4 xReg[4];
    bf16x8 bReg0, bReg1;

    auto LOADS_A = [&](int t) {
        const float* p = Xb + (size_t)row * FF + t * 32 + kh * 16;
        #pragma unroll
        for (int i = 0; i < 4; i++) sA[i] = *(const float4*)(p + 4 * i);
    };
    auto LOADS_B = [&](int t) {
        const float* p = Xb + (size_t)row * FF + t * 32 + kh * 16;
        #pragma unroll
        for (int i = 0; i < 4; i++) sB[i] = *(const float4*)(p + 4 * i);
    };
    auto LOADX = [&](int t) {
        const float* p = xb + t * 32 + kh * 16;
        #pragma unroll
        for (int i = 0; i < 4; i++) xReg[i] = *(const float4*)(p + 4 * i);
    };
    auto LOADB = [&](int t) {
        const __bf16* pW = Wt + (size_t)row * FF + t * 32 + kh * 16;
        bReg0 = *(const bf16x8*)(pW);
        bReg1 = *(const bf16x8*)(pW + 8);
    };
    auto WRITE_FROM_A = [&](int buf) {
        __bf16 d[16];
        #pragma unroll
        for (int i = 0; i < 4; i++) {
            d[4*i+0] = (__bf16)(xReg[i].x - sA[i].x);
            d[4*i+1] = (__bf16)(xReg[i].y - sA[i].y);
            d[4*i+2] = (__bf16)(xReg[i].z - sA[i].z);
            d[4*i+3] = (__bf16)(xReg[i].w - sA[i].w);
        }
        *(bf16x8*)&lA[buf][kh*2+0][row][0] = *(bf16x8*)&d[0];
        *(bf16x8*)&lA[buf][kh*2+1][row][0] = *(bf16x8*)&d[8];
        *(bf16x8*)&lB[buf][kh*2+0][row][0] = bReg0;
        *(bf16x8*)&lB[buf][kh*2+1][row][0] = bReg1;
    };
    auto WRITE_FROM_B = [&](int buf) {
        __bf16 d[16];
        #pragma unroll
        for (int i = 0; i < 4; i++) {
            d[4*i+0] = (__bf16)(xReg[i].x - sB[i].x);
            d[4*i+1] = (__bf16)(xReg[i].y - sB[i].y);
            d[4*i+2] = (__bf16)(xReg[i].z - sB[i].z);
            d[4*i+3] = (__bf16)(xReg[i].w - sB[i].w);
        }
        *(bf16x8*)&lA[buf][kh*2+0][row][0] = *(bf16x8*)&d[0];
        *(bf16x8*)&lA[buf][kh*2+1][row][0] = *(bf16x8*)&d[8];
        *(bf16x8*)&lB[buf][kh*2+0][row][0] = bReg0;
        *(bf16x8*)&lB[buf][kh*2+1][row][0] = bReg1;
    };
    auto MFMA_STEP = [&](int buf) {
        bf16x8 af[4], bfr[4];
        #pragma unroll
        for (int m = 0; m < 4; m++)
            af[m] = *(const bf16x8*)&lA[buf][lg][wrow + m * 16 + lr][0];
        #pragma unroll
        for (int n = 0; n < 4; n++)
            bfr[n] = *(const bf16x8*)&lB[buf][lg][wcol + n * 16 + lr][0];
        #pragma unroll
        for (int m = 0; m < 4; m++)
            #pragma unroll
            for (int n = 0; n < 4; n++)
                acc[m][n] = __builtin_amdgcn_mfma_f32_16x16x32_bf16(af[m], bfr[n], acc[m][n], 0, 0, 0);
    };

    // ---- Prologue: sets A=t0, B=t1 in flight; write t0 -> buf0 ----
    LOADS_A(0);
    LOADS_B(1);
    LOADX(0);
    LOADB(0);
    WRITE_FROM_A(0);          // dep-wait drains prologue loads (once, negligible)
    BAR_RELAXED();

    // ---- K-loop: at step t: issue [x,W](t+1) then [sx](t+2); compute t; write t+1 ----
    #pragma unroll
    for (int t = 0; t < 16; t++) {
        const int cur = t & 1;
        if (t + 1 < 16) { LOADX(t + 1); LOADB(t + 1); }   // older: WRITE's newest dep
        if (t + 2 < 16) {
            if ((t & 1) == 0) LOADS_A(t + 2);             // newest: survives the wait
            else              LOADS_B(t + 2);
        }
        MFMA_STEP(cur);
        if (t + 1 < 16) {
            if ((t & 1) == 0) WRITE_FROM_B(cur ^ 1);      // t+1 lives in the other set
            else              WRITE_FROM_A(cur ^ 1);
        }
        BAR_RELAXED();
    }

    // ---- prefetch first 8 support_y rows (independent of wv) ----
    const float* ybase = y + ((size_t)b * SS + srow0) * CC + tid * 4;
    float4 yReg[8];
    if (tid < 250) {
        #pragma unroll
        for (int i = 0; i < 8; i++)
            yReg[i] = *(const float4*)(ybase + (size_t)i * CC);
    }

    // ---- Epilogue: per-row ||.||^2 -> wv[row] = exp(-sqrt(.)) ----
    // C/D layout: col = wcol + n*16 + lr ; row = wrow + m*16 + lg*4 + j
    float rp[4][4];
    #pragma unroll
    for (int m = 0; m < 4; m++)
        #pragma unroll
        for (int j = 0; j < 4; j++) {
            float s = 0.f;
            #pragma unroll
            for (int n = 0; n < 4; n++) { float v = acc[m][n][j]; s += v * v; }
            rp[m][j] = s;
        }
    #pragma unroll
    for (int mask = 1; mask < 16; mask <<= 1)
        #pragma unroll
        for (int m = 0; m < 4; m++)
            #pragma unroll
            for (int j = 0; j < 4; j++)
                rp[m][j] += __shfl_xor(rp[m][j], mask);

    if (lr == 0) {
        #pragma unroll
        for (int m = 0; m < 4; m++)
            #pragma unroll
            for (int j = 0; j < 4; j++)
                scp[w & 1][wrow + m * 16 + lg * 4 + j] = rp[m][j];
    }
    __syncthreads();
    if (tid < 128)
        wv[tid] = expf(-sqrtf(scp[0][tid] + scp[1][tid]));
    __syncthreads();

    // partial denominator: wave 0 reduces wv[0..127]
    if (w == 0) {
        float d = wv[lane] + wv[lane + 64];
        #pragma unroll
        for (int mask = 1; mask < 64; mask <<= 1)
            d += __shfl_xor(d, mask);
        if (lane == 0) pden[b * 64 + chunk] = d;
    }

    // ---- Phase 2: weighted partial sum over support_y (128 rows x 1000 classes) ----
    if (tid < 250) {
        float a0 = 0.f, a1 = 0.f, a2 = 0.f, a3 = 0.f;
        for (int r0 = 0; r0 < 128; r0 += 8) {
            #pragma unroll
            for (int i = 0; i < 8; i++) {
                float4 v = yReg[i];
                float wgt = wv[r0 + i];
                a0 += wgt * v.x; a1 += wgt * v.y; a2 += wgt * v.z; a3 += wgt * v.w;
                if (r0 + 8 + i < 128)
                    yReg[i] = *(const float4*)(ybase + (size_t)(r0 + 8 + i) * CC);
            }
        }
        float4 res = {a0, a1, a2, a3};
        *(float4*)(pout + ((size_t)(b * 64 + chunk)) * CC + tid * 4) = res;
    }
}

// ---------------- K4: final reduction over 64 chunks ----------------
__global__ void k4_final(const float* __restrict__ pout, const float* __restrict__ pden,
                         float* __restrict__ out) {
    int idx = blockIdx.x * 256 + threadIdx.x;
    if (idx >= BB * CC) return;
    int b = idx / CC, c = idx % CC;
    float den = 0.f;
    #pragma unroll 8
    for (int k = 0; k < 64; k++) den += pden[b * 64 + k];
    float num = 0.f;
    #pragma unroll 8
    for (int k = 0; k < 64; k++) num += pout[((size_t)(b * 64 + k)) * CC + c];
    out[idx] = num / den;
}

extern "C" void kernel_launch(void* const* d_in, const int* in_sizes, int n_in,
                              void* d_out, int out_size, void* d_ws, size_t ws_size,
                              hipStream_t stream) {
    const float* x  = (const float*)d_in[0];
    const float* sx = (const float*)d_in[1];
    const float* sy = (const float*)d_in[2];
    const float* W  = (const float*)d_in[3];

    char* ws = (char*)d_ws;
    __bf16* Wt   = (__bf16*)(ws);                        // 131072 B
    float*  pout = (float*)(ws + 131072);                // 2048000 B
    float*  pden = (float*)(ws + 131072 + 2048000);      // 2048 B

    k0_wt<<<256, 256, 0, stream>>>(W, Wt);
    k_fused<<<512, 256, 0, stream>>>(x, sx, Wt, sy, pout, pden);
    k4_final<<<32, 256, 0, stream>>>(pout, pden, (float*)d_out);
}